// Round 6
// baseline (1012.038 us; speedup 1.0000x reference)
//
#include <hip/hip_runtime.h>
#include <stdint.h>

typedef _Float16 f16x8 __attribute__((ext_vector_type(8)));
typedef _Float16 f16x4 __attribute__((ext_vector_type(4)));
typedef float    f32x4 __attribute__((ext_vector_type(4)));

#define S_LEN 4096
#define D_DIM 64
#define NB 16
constexpr size_t NE = (size_t)NB * S_LEN * D_DIM;  // 4,194,304

// ---- prep 1: K f32 -> f16 (same layout) ----
__global__ __launch_bounds__(256) void k_half(const float* __restrict__ in,
                                              _Float16* __restrict__ out) {
  int i = blockIdx.x * 256 + threadIdx.x;  // float4 index
  f32x4 x = reinterpret_cast<const f32x4*>(in)[i];
  f16x4 o;
  o[0] = (_Float16)x[0]; o[1] = (_Float16)x[1];
  o[2] = (_Float16)x[2]; o[3] = (_Float16)x[3];
  reinterpret_cast<f16x4*>(out)[i] = o;
}

// ---- prep 2: V[b][k][d] -> Vt[b][d][k] f16 ----
__global__ __launch_bounds__(256) void v_prep(const float* __restrict__ v,
                                              _Float16* __restrict__ vt) {
  __shared__ float t[64][65];
  int b = blockIdx.x >> 6, kt = blockIdx.x & 63;
  int c = threadIdx.x & 63, rg = threadIdx.x >> 6;
#pragma unroll
  for (int j = 0; j < 16; ++j)
    t[rg + 4 * j][c] = v[((size_t)b * S_LEN + kt * 64 + rg + 4 * j) * D_DIM + c];
  __syncthreads();
#pragma unroll
  for (int j = 0; j < 16; ++j) {
    int d = rg + 4 * j;
    vt[((size_t)b * D_DIM + d) * S_LEN + kt * 64 + c] = (_Float16)t[c][d];
  }
}

// ---- main fused attention: barrier-free, LDS-free, plain (L2 write-back) stores ----
// 1024 blocks x 256 threads; block = (b, 64 q-rows); wave owns 16 q-rows (q = lane&15).
// Swapped QK^T: sa[nf][r] = S[q = qrow][k = kt*64 + nf*16 + 4*lh + r].
// K fragments read directly from L1/L2 (8KB tile shared by 64 blocks/batch).
__global__ __launch_bounds__(256, 4) void attn_k(const float* __restrict__ q,
                                                 const _Float16* __restrict__ kh,
                                                 const _Float16* __restrict__ vt,
                                                 float* __restrict__ ctx,
                                                 float* __restrict__ att) {
  const int tid = threadIdx.x, w = tid >> 6, lane = tid & 63;
  const int l15 = lane & 15, lh = lane >> 4;
  const int bid = blockIdx.x;
  const int logical = (bid & 7) * 128 + (bid >> 3);  // 2 batches per XCD
  const int b = logical >> 6, qt = logical & 63;
  const int qrow = qt * 64 + w * 16 + l15;

  // Q fragment f16 (B operand: col=q at l15; k16 = 8*lh+i -> d = ds*32+8*lh+i)
  f16x8 qf[2];
#pragma unroll
  for (int ds = 0; ds < 2; ++ds) {
    const float* qp = q + ((size_t)b * S_LEN + qrow) * D_DIM + ds * 32 + 8 * lh;
    f32x4 a = *reinterpret_cast<const f32x4*>(qp);
    f32x4 c4 = *reinterpret_cast<const f32x4*>(qp + 4);
#pragma unroll
    for (int i = 0; i < 4; ++i) {
      qf[ds][i] = (_Float16)a[i];
      qf[ds][i + 4] = (_Float16)c4[i];
    }
  }

  // per-lane K fragment base: row l15 (within 16-row nf group), d-chunk 8*lh
  const _Float16* klbase = kh + (size_t)b * S_LEN * D_DIM + l15 * D_DIM + 8 * lh;

  auto qk = [&](int kt, f32x4(&sa)[4]) {
    const _Float16* p = klbase + (size_t)kt * 4096;
#pragma unroll
    for (int ds = 0; ds < 2; ++ds)
#pragma unroll
      for (int nf = 0; nf < 4; ++nf) {
        f16x8 kf = *reinterpret_cast<const f16x8*>(p + nf * 1024 + ds * 32);
        sa[nf] = __builtin_amdgcn_mfma_f32_16x16x32_f16(kf, qf[ds], sa[nf], 0, 0, 0);
      }
  };

  constexpr float CEXP = 0.18033688011112042f;  // log2(e) / 8

  // ---- pass 1: softmax denominator (m fixed at 0; |s| <~ 9, exp2 safe) ----
  float lsum = 0.f;
#pragma unroll 4
  for (int kt = 0; kt < 64; ++kt) {
    f32x4 sa[4] = {};
    qk(kt, sa);
#pragma unroll
    for (int nf = 0; nf < 4; ++nf)
#pragma unroll
      for (int r = 0; r < 4; ++r) lsum += exp2f(sa[nf][r] * CEXP);
  }
  lsum += __shfl_xor(lsum, 16);
  lsum += __shfl_xor(lsum, 32);
  const float linv = 1.0f / lsum;

  // ---- pass 2: recompute scores, write att (float4), PV via 16x16x16 f16 ----
  f32x4 ca[4] = {};
  float* attrow = att + ((size_t)b * S_LEN + qrow) * S_LEN;
  const _Float16* vbase = vt + (size_t)b * D_DIM * S_LEN + (size_t)l15 * S_LEN;
#pragma unroll 2
  for (int kt = 0; kt < 64; ++kt) {
    f32x4 sa[4] = {};
    qk(kt, sa);
    f16x4 pb[4];
#pragma unroll
    for (int nf = 0; nf < 4; ++nf) {
      f32x4 p;
      p[0] = exp2f(sa[nf][0] * CEXP) * linv;
      p[1] = exp2f(sa[nf][1] * CEXP) * linv;
      p[2] = exp2f(sa[nf][2] * CEXP) * linv;
      p[3] = exp2f(sa[nf][3] * CEXP) * linv;
      *reinterpret_cast<f32x4*>(attrow + kt * 64 + nf * 16 + 4 * lh) = p;
      pb[nf][0] = (_Float16)p[0];
      pb[nf][1] = (_Float16)p[1];
      pb[nf][2] = (_Float16)p[2];
      pb[nf][3] = (_Float16)p[3];
    }
#pragma unroll
    for (int nf = 0; nf < 4; ++nf) {
      const _Float16* vp = vbase + kt * 64 + nf * 16 + 4 * lh;
#pragma unroll
      for (int dn = 0; dn < 4; ++dn) {
        f16x4 va = *reinterpret_cast<const f16x4*>(vp + (size_t)dn * 16 * S_LEN);
        ca[dn] = __builtin_amdgcn_mfma_f32_16x16x16f16(va, pb[nf], ca[dn], 0, 0, 0);
      }
    }
  }
#pragma unroll
  for (int dn = 0; dn < 4; ++dn)
    *reinterpret_cast<f32x4*>(ctx + ((size_t)b * S_LEN + qrow) * D_DIM + dn * 16 + 4 * lh) =
        ca[dn];

  (void)w;
}

extern "C" void kernel_launch(void* const* d_in, const int* in_sizes, int n_in,
                              void* d_out, int out_size, void* d_ws, size_t ws_size,
                              hipStream_t stream) {
  const float* q = (const float*)d_in[0];
  const float* k = (const float*)d_in[1];
  const float* v = (const float*)d_in[2];
  float* ctx = (float*)d_out;  // [16][4096][64]
  float* att = ctx + NE;       // [16][4096][4096]

  _Float16* kh = (_Float16*)d_ws;                    // 8.39 MB
  _Float16* vt = (_Float16*)((char*)d_ws + 2 * NE);  // 8.39 MB

  k_half<<<(int)(NE / 1024), 256, 0, stream>>>(k, kh);
  v_prep<<<NB * 64, 256, 0, stream>>>(v, vt);
  attn_k<<<1024, 256, 0, stream>>>(q, kh, vt, ctx, att);
}

// Round 7
// 931.766 us; speedup vs baseline: 1.0862x; 1.0862x over previous
//
#include <hip/hip_runtime.h>
#include <stdint.h>

typedef _Float16 f16x8 __attribute__((ext_vector_type(8)));
typedef _Float16 f16x4 __attribute__((ext_vector_type(4)));
typedef float    f32x4 __attribute__((ext_vector_type(4)));

#define S_LEN 4096
#define D_DIM 64
#define NB 16
constexpr size_t NE = (size_t)NB * S_LEN * D_DIM;  // 4,194,304

// ---- prep 1: K -> fragment-ordered f16 stream K3 ----
// tile t = b*64+kt holds 4096 halfs: [ds(2)][nf(4)][lane(64)][i(8)]
// value = K[b][kt*64 + nf*16 + (lane&15)][ds*32 + (lane>>4)*8 + i]
// In the main kernel, load g=ds*4+nf is 64 lanes x 16B fully contiguous.
__global__ __launch_bounds__(256) void k_prep3(const float* __restrict__ k,
                                               _Float16* __restrict__ k3) {
  int g = blockIdx.x * 256 + threadIdx.x;  // 8-half chunk id
  int tile = g >> 9, c = g & 511;
  int grp = c >> 6, lane = c & 63;
  int ds = grp >> 2, nf = grp & 3;
  int row = nf * 16 + (lane & 15);
  int d0 = ds * 32 + ((lane >> 4) << 3);
  const float* src = k + ((size_t)tile * 64 + row) * D_DIM + d0;
  f32x4 a = *reinterpret_cast<const f32x4*>(src);
  f32x4 b4 = *reinterpret_cast<const f32x4*>(src + 4);
  f16x8 o;
#pragma unroll
  for (int i = 0; i < 4; ++i) {
    o[i] = (_Float16)a[i];
    o[i + 4] = (_Float16)b4[i];
  }
  *reinterpret_cast<f16x8*>(k3 + (size_t)g * 8) = o;
}

// ---- prep 2: V -> fragment-ordered f16 stream V3 ----
// tile t = b*64+kt holds 4096 halfs: [nf(4)][dn(4)][lane(64)][i(4)]
// value = V[b][kt*64 + nf*16 + 4*(lane>>4) + i][dn*16 + (lane&15)]
// Main-kernel load g=nf*4+dn is 64 lanes x 8B fully contiguous.
__global__ __launch_bounds__(256) void v_prep3(const float* __restrict__ v,
                                               _Float16* __restrict__ v3) {
  __shared__ float t[64][65];  // [k_local][d]
  int tile = blockIdx.x;       // b*64 + kt
  int c = threadIdx.x & 63, rg = threadIdx.x >> 6;
#pragma unroll
  for (int j = 0; j < 16; ++j)
    t[rg + 4 * j][c] = v[((size_t)tile * 64 + rg + 4 * j) * D_DIM + c];
  __syncthreads();
  _Float16* dst = v3 + (size_t)tile * 4096;
#pragma unroll
  for (int j = 0; j < 4; ++j) {
    int cc = threadIdx.x + 256 * j;  // chunk id 0..1023
    int grp = cc >> 6, lane = cc & 63;
    int nf = grp >> 2, dn = grp & 3;
    int kl = nf * 16 + ((lane >> 4) << 2);
    int d = dn * 16 + (lane & 15);
    f16x4 o;
#pragma unroll
    for (int i = 0; i < 4; ++i) o[i] = (_Float16)t[kl + i][d];
    *reinterpret_cast<f16x4*>(dst + (size_t)cc * 4) = o;
  }
}

// ---- main fused attention: barrier-free, LDS-free, fully-coalesced streams ----
// 1024 blocks x 256 threads; block = (b, 64 q-rows); wave owns 16 q-rows (q = lane&15).
// Swapped QK^T: sa[nf][r] = S[q = qrow][k = kt*64 + nf*16 + 4*lh + r].
__global__ __launch_bounds__(256, 4) void attn_k(const float* __restrict__ q,
                                                 const _Float16* __restrict__ k3,
                                                 const _Float16* __restrict__ v3,
                                                 float* __restrict__ ctx,
                                                 float* __restrict__ att) {
  const int tid = threadIdx.x, w = tid >> 6, lane = tid & 63;
  const int l15 = lane & 15, lh = lane >> 4;
  const int bid = blockIdx.x;
  const int logical = (bid & 7) * 128 + (bid >> 3);  // 2 batches per XCD
  const int b = logical >> 6, qt = logical & 63;
  const int qrow = qt * 64 + w * 16 + l15;

  // Q fragment f16 (B operand: col=q at l15; k16 = 8*lh+i -> d = ds*32+8*lh+i)
  f16x8 qf[2];
#pragma unroll
  for (int ds = 0; ds < 2; ++ds) {
    const float* qp = q + ((size_t)b * S_LEN + qrow) * D_DIM + ds * 32 + 8 * lh;
    f32x4 a = *reinterpret_cast<const f32x4*>(qp);
    f32x4 c4 = *reinterpret_cast<const f32x4*>(qp + 4);
#pragma unroll
    for (int i = 0; i < 4; ++i) {
      qf[ds][i] = (_Float16)a[i];
      qf[ds][i + 4] = (_Float16)c4[i];
    }
  }

  const _Float16* ktile0 = k3 + (size_t)(b * 64) * 4096 + lane * 8;
  const _Float16* vtile0 = v3 + (size_t)(b * 64) * 4096 + lane * 4;

  auto qk = [&](int kt, f32x4(&sa)[4]) {
    const _Float16* p = ktile0 + (size_t)kt * 4096;
    f16x8 kf[8];
#pragma unroll
    for (int g = 0; g < 8; ++g) kf[g] = *reinterpret_cast<const f16x8*>(p + g * 512);
#pragma unroll
    for (int ds = 0; ds < 2; ++ds)
#pragma unroll
      for (int nf = 0; nf < 4; ++nf)
        sa[nf] = __builtin_amdgcn_mfma_f32_16x16x32_f16(kf[ds * 4 + nf], qf[ds], sa[nf], 0, 0, 0);
  };

  constexpr float CEXP = 0.18033688011112042f;  // log2(e) / 8

  // ---- pass 1: softmax denominator (m fixed at 0; |s| <~ 9, exp2 safe) ----
  float lsum = 0.f;
  for (int kt = 0; kt < 64; ++kt) {
    f32x4 sa[4] = {};
    qk(kt, sa);
#pragma unroll
    for (int nf = 0; nf < 4; ++nf)
#pragma unroll
      for (int r = 0; r < 4; ++r) lsum += exp2f(sa[nf][r] * CEXP);
  }
  lsum += __shfl_xor(lsum, 16);
  lsum += __shfl_xor(lsum, 32);
  const float linv = 1.0f / lsum;

  // ---- pass 2: recompute scores, write att (float4), PV via 16x16x16 f16 ----
  f32x4 ca[4] = {};
  float* attrow = att + ((size_t)b * S_LEN + qrow) * S_LEN;
  for (int kt = 0; kt < 64; ++kt) {
    f32x4 sa[4] = {};
    qk(kt, sa);
    // V stream for this tile (16 x 512B coalesced loads) — issue early
    const _Float16* vp = vtile0 + (size_t)kt * 4096;
    f16x4 vv[16];
#pragma unroll
    for (int g = 0; g < 16; ++g) vv[g] = *reinterpret_cast<const f16x4*>(vp + g * 256);
    f16x4 pb[4];
#pragma unroll
    for (int nf = 0; nf < 4; ++nf) {
      f32x4 p;
      p[0] = exp2f(sa[nf][0] * CEXP) * linv;
      p[1] = exp2f(sa[nf][1] * CEXP) * linv;
      p[2] = exp2f(sa[nf][2] * CEXP) * linv;
      p[3] = exp2f(sa[nf][3] * CEXP) * linv;
      *reinterpret_cast<f32x4*>(attrow + kt * 64 + nf * 16 + 4 * lh) = p;
      pb[nf][0] = (_Float16)p[0];
      pb[nf][1] = (_Float16)p[1];
      pb[nf][2] = (_Float16)p[2];
      pb[nf][3] = (_Float16)p[3];
    }
#pragma unroll
    for (int nf = 0; nf < 4; ++nf)
#pragma unroll
      for (int dn = 0; dn < 4; ++dn)
        ca[dn] = __builtin_amdgcn_mfma_f32_16x16x16f16(vv[nf * 4 + dn], pb[nf], ca[dn], 0, 0, 0);
  }
#pragma unroll
  for (int dn = 0; dn < 4; ++dn)
    *reinterpret_cast<f32x4*>(ctx + ((size_t)b * S_LEN + qrow) * D_DIM + dn * 16 + 4 * lh) =
        ca[dn];
}

extern "C" void kernel_launch(void* const* d_in, const int* in_sizes, int n_in,
                              void* d_out, int out_size, void* d_ws, size_t ws_size,
                              hipStream_t stream) {
  const float* q = (const float*)d_in[0];
  const float* k = (const float*)d_in[1];
  const float* v = (const float*)d_in[2];
  float* ctx = (float*)d_out;  // [16][4096][64]
  float* att = ctx + NE;       // [16][4096][4096]

  _Float16* k3 = (_Float16*)d_ws;                    // 8.39 MB
  _Float16* v3 = (_Float16*)((char*)d_ws + 2 * NE);  // 8.39 MB

  k_prep3<<<(int)(NE / 8 / 256), 256, 0, stream>>>(k, k3);
  v_prep3<<<NB * 64, 256, 0, stream>>>(v, v3);
  attn_k<<<1024, 256, 0, stream>>>(q, k3, v3, ctx, att);
}

// Round 8
// 450.728 us; speedup vs baseline: 2.2453x; 2.0672x over previous
//
#include <hip/hip_runtime.h>
#include <stdint.h>

typedef _Float16 f16x8 __attribute__((ext_vector_type(8)));
typedef _Float16 f16x4 __attribute__((ext_vector_type(4)));
typedef float    f32x4 __attribute__((ext_vector_type(4)));

#define S_LEN 4096
#define D_DIM 64
#define NB 16
constexpr size_t NE = (size_t)NB * S_LEN * D_DIM;  // 4,194,304

// ---- prep 1: K f32 -> f16 (row-major, same layout) ----
__global__ __launch_bounds__(256) void k_half(const float* __restrict__ in,
                                              _Float16* __restrict__ out) {
  int i = blockIdx.x * 256 + threadIdx.x;  // float4 index
  f32x4 x = reinterpret_cast<const f32x4*>(in)[i];
  f16x4 o;
  o[0] = (_Float16)x[0]; o[1] = (_Float16)x[1];
  o[2] = (_Float16)x[2]; o[3] = (_Float16)x[3];
  reinterpret_cast<f16x4*>(out)[i] = o;
}

// ---- prep 2: V -> fragment-ordered f16 stream, 16B-paired ----
// tile t = b*64+kt holds 4096 halfs laid out [g2(8)][lane(64)][h(2)][i(4)],
// where frag g = g2*2+h (g = nf*4+dn) and
// value = V[tile*64 + nf*16 + 4*(lane>>4) + i][dn*16 + (lane&15)].
// Main-kernel load g2 is 64 lanes x 16B fully contiguous.
__global__ __launch_bounds__(256) void v_prep3(const float* __restrict__ v,
                                               _Float16* __restrict__ v3) {
  __shared__ float t[64][65];  // [k_local][d]
  int tile = blockIdx.x;       // b*64 + kt
  int c = threadIdx.x & 63, rg = threadIdx.x >> 6;
#pragma unroll
  for (int j = 0; j < 16; ++j)
    t[rg + 4 * j][c] = v[((size_t)tile * 64 + rg + 4 * j) * D_DIM + c];
  __syncthreads();
  _Float16* dst = v3 + (size_t)tile * 4096;
#pragma unroll
  for (int j = 0; j < 4; ++j) {
    int cc = threadIdx.x + 256 * j;  // frag-chunk id 0..1023
    int g = cc >> 6, lane = cc & 63;
    int nf = g >> 2, dn = g & 3;
    int kl = nf * 16 + ((lane >> 4) << 2);
    int d = dn * 16 + (lane & 15);
    f16x4 o;
#pragma unroll
    for (int i = 0; i < 4; ++i) o[i] = (_Float16)t[kl + i][d];
    *reinterpret_cast<f16x4*>(dst + ((g >> 1) << 9) + lane * 8 + ((g & 1) << 2)) = o;
  }
}

#define PIPE_BARRIER()                                      \
  do {                                                      \
    asm volatile("s_waitcnt lgkmcnt(0)" ::: "memory");      \
    __builtin_amdgcn_s_barrier();                           \
    __builtin_amdgcn_sched_barrier(0);                      \
  } while (0)

// ---- main fused attention: double-buffered LDS pipeline, no vmcnt drain ----
// 1024 blocks x 256 threads; block = (b, 64 q-rows); wave owns 16 q-rows (q = lane&15).
// Swapped QK^T: sa[nf][r] = S[q = qrow][k = kt*64 + nf*16 + 4*lh + r].
__global__ __launch_bounds__(256, 4) void attn_k(const float* __restrict__ q,
                                                 const _Float16* __restrict__ kh,
                                                 const _Float16* __restrict__ v3,
                                                 float* __restrict__ ctx,
                                                 float* __restrict__ att) {
  __shared__ _Float16 ktile[2][4096];  // 2 x 8KB double buffer
  const int tid = threadIdx.x, w = tid >> 6, lane = tid & 63;
  const int l15 = lane & 15, lh = lane >> 4;
  const int bid = blockIdx.x;
  const int logical = (bid & 7) * 128 + (bid >> 3);  // 2 batches per XCD
  const int b = logical >> 6, qt = logical & 63;
  const int qrow = qt * 64 + w * 16 + l15;

  // Q fragment f16 (B operand: col=q at l15; k16 = 8*lh+i -> d = ds*32+8*lh+i)
  f16x8 qf[2];
#pragma unroll
  for (int ds = 0; ds < 2; ++ds) {
    const float* qp = q + ((size_t)b * S_LEN + qrow) * D_DIM + ds * 32 + 8 * lh;
    f32x4 a = *reinterpret_cast<const f32x4*>(qp);
    f32x4 c4 = *reinterpret_cast<const f32x4*>(qp + 4);
#pragma unroll
    for (int i = 0; i < 4; ++i) {
      qf[ds][i] = (_Float16)a[i];
      qf[ds][i + 4] = (_Float16)c4[i];
    }
  }

  // staging: thread owns chunks c0 = tid (rows 0..31), c1 = tid+256 (rows 32..63);
  // chunk c = row r (c>>3) x logical d-chunk s (c&7); LDS slot = s ^ (r&7).
  const _Float16* khb = kh + (size_t)b * S_LEN * D_DIM;
  const int c0 = tid, c1 = tid + 256;
  const int off0 = (c0 >> 3) * 128 + ((((c0 & 7) ^ ((c0 >> 3) & 7))) << 4);
  const int off1 = (c1 >> 3) * 128 + ((((c1 & 7) ^ ((c1 >> 3) & 7))) << 4);
  f16x8 st0, st1;
  auto load_st = [&](int kt) {
    const _Float16* src = khb + (size_t)kt * 4096;
    st0 = *reinterpret_cast<const f16x8*>(src + c0 * 8);
    st1 = *reinterpret_cast<const f16x8*>(src + c1 * 8);
  };
  auto write_st = [&](int buf) {
    char* base = (char*)&ktile[buf][0];
    *reinterpret_cast<f16x8*>(base + off0) = st0;
    *reinterpret_cast<f16x8*>(base + off1) = st1;
  };

  const int swz = l15 & 7;
  auto qk = [&](int cur, f32x4(&sa)[4]) {
    const char* base = (const char*)&ktile[cur][0];
#pragma unroll
    for (int ds = 0; ds < 2; ++ds) {
      const int ch = (((ds << 2) | lh) ^ swz) << 4;  // swizzled slot for d-chunk ds*4+lh
#pragma unroll
      for (int nf = 0; nf < 4; ++nf) {
        f16x8 kf = *reinterpret_cast<const f16x8*>(base + (nf * 16 + l15) * 128 + ch);
        sa[nf] = __builtin_amdgcn_mfma_f32_16x16x32_f16(kf, qf[ds], sa[nf], 0, 0, 0);
      }
    }
  };

  constexpr float CEXP = 0.18033688011112042f;  // log2(e) / 8

  // ================= pass 1: softmax denominator (m = 0; |s| <~ 9) =================
  load_st(0);
  write_st(0);
  PIPE_BARRIER();
  load_st(1);
  float lsum = 0.f;
  for (int t = 0; t < 64; ++t) {
    const int cur = t & 1;
    write_st(cur ^ 1);                    // stage tile t+1 (regs from last iter)
    load_st(t + 2 < 64 ? t + 2 : 63);     // issue loads for t+2, consumed next iter
    f32x4 sa[4] = {};
    qk(cur, sa);
#pragma unroll
    for (int nf = 0; nf < 4; ++nf)
#pragma unroll
      for (int r = 0; r < 4; ++r) lsum += exp2f(sa[nf][r] * CEXP);
    PIPE_BARRIER();
  }
  lsum += __shfl_xor(lsum, 16);
  lsum += __shfl_xor(lsum, 32);
  const float linv = 1.0f / lsum;

  // ================= pass 2: scores -> att store + PV =================
  load_st(0);
  write_st(0);
  PIPE_BARRIER();
  load_st(1);
  f32x4 ca[4] = {};
  float* attrow = att + ((size_t)b * S_LEN + qrow) * S_LEN;
  const _Float16* v3b = v3 + (size_t)(b * 64) * 4096 + lane * 8;
  for (int t = 0; t < 64; ++t) {
    const int cur = t & 1;
    write_st(cur ^ 1);
    load_st(t + 2 < 64 ? t + 2 : 63);
    // V stream for this tile: 8 x 16B fully-coalesced loads, consumed after qk/exp
    const _Float16* vp = v3b + (size_t)t * 4096;
    f16x8 vv8[8];
#pragma unroll
    for (int g2 = 0; g2 < 8; ++g2)
      vv8[g2] = *reinterpret_cast<const f16x8*>(vp + (size_t)g2 * 512);
    f32x4 sa[4] = {};
    qk(cur, sa);
    f16x4 pb[4];
#pragma unroll
    for (int nf = 0; nf < 4; ++nf) {
      f32x4 p;
      p[0] = exp2f(sa[nf][0] * CEXP) * linv;
      p[1] = exp2f(sa[nf][1] * CEXP) * linv;
      p[2] = exp2f(sa[nf][2] * CEXP) * linv;
      p[3] = exp2f(sa[nf][3] * CEXP) * linv;
      *reinterpret_cast<f32x4*>(attrow + t * 64 + nf * 16 + 4 * lh) = p;
      pb[nf][0] = (_Float16)p[0];
      pb[nf][1] = (_Float16)p[1];
      pb[nf][2] = (_Float16)p[2];
      pb[nf][3] = (_Float16)p[3];
    }
#pragma unroll
    for (int nf = 0; nf < 4; ++nf)
#pragma unroll
      for (int dn = 0; dn < 4; ++dn) {
        const int g = nf * 4 + dn;
        f16x4 vf = (g & 1) ? __builtin_shufflevector(vv8[g >> 1], vv8[g >> 1], 4, 5, 6, 7)
                           : __builtin_shufflevector(vv8[g >> 1], vv8[g >> 1], 0, 1, 2, 3);
        ca[dn] = __builtin_amdgcn_mfma_f32_16x16x16f16(vf, pb[nf], ca[dn], 0, 0, 0);
      }
    PIPE_BARRIER();
  }
#pragma unroll
  for (int dn = 0; dn < 4; ++dn)
    *reinterpret_cast<f32x4*>(ctx + ((size_t)b * S_LEN + qrow) * D_DIM + dn * 16 + 4 * lh) =
        ca[dn];
}

extern "C" void kernel_launch(void* const* d_in, const int* in_sizes, int n_in,
                              void* d_out, int out_size, void* d_ws, size_t ws_size,
                              hipStream_t stream) {
  const float* q = (const float*)d_in[0];
  const float* k = (const float*)d_in[1];
  const float* v = (const float*)d_in[2];
  float* ctx = (float*)d_out;  // [16][4096][64]
  float* att = ctx + NE;       // [16][4096][4096]

  _Float16* kh = (_Float16*)d_ws;                    // 8.39 MB
  _Float16* v3 = (_Float16*)((char*)d_ws + 2 * NE);  // 8.39 MB

  k_half<<<(int)(NE / 1024), 256, 0, stream>>>(k, kh);
  v_prep3<<<NB * 64, 256, 0, stream>>>(v, v3);
  attn_k<<<1024, 256, 0, stream>>>(q, kh, v3, ctx, att);
}